// Round 1
// baseline (200.389 us; speedup 1.0000x reference)
//
#include <hip/hip_runtime.h>
#include <hip/hip_bf16.h>

typedef __attribute__((ext_vector_type(8))) short short8;
typedef __attribute__((ext_vector_type(4))) float f32x4;
typedef __attribute__((ext_vector_type(2))) unsigned int u32x2;

#define HH   32
#define CINN 32
#define COUTT 64
#define KNUM 15

__device__ __forceinline__ unsigned short f2bf(float f) {
    unsigned u = __float_as_uint(f);
    u += 0x7fffu + ((u >> 16) & 1u);      // round-to-nearest-even
    return (unsigned short)(u >> 16);
}

__launch_bounds__(256, 2)
__global__ void kpconv_kernel(const float* __restrict__ query,
                              const float* __restrict__ support,
                              const int*   __restrict__ edge,
                              const float* __restrict__ feats,
                              const float* __restrict__ kpts,
                              const float* __restrict__ kvals,
                              float* __restrict__ out,
                              int nPts, int nBatch) {
    // LDS: Kv B-frags 61440B + stage-2 A-frags 15360B + xyz 4096B = 80896B -> 2 blocks/CU
    __shared__ unsigned short kv_lds[KNUM * 4 * 64 * 8];
    __shared__ unsigned short af_lds[KNUM * 64 * 8];
    __shared__ f32x4 xyz[4][2][32];

    const int tid  = threadIdx.x;
    const int wave = tid >> 6;
    const int lane = tid & 63;
    const int g    = lane >> 4;
    const int low  = lane & 15;

    // ---- one-time: stage Kv into LDS in stage-2 B-frag order ----
    // frag element: [s][tile][lane][i] = Kv[s][c=(lane>>4)*8+i][o=tile*16+(lane&15)]
    for (int e = tid; e < KNUM * 4 * 64 * 8; e += 256) {
        int i    = e & 7;
        int ln   = (e >> 3) & 63;
        int tile = (e >> 9) & 3;
        int s    = e >> 11;
        int c    = ((ln >> 4) << 3) + i;
        int o    = (tile << 4) + (ln & 15);
        kv_lds[e] = f2bf(kvals[(s * CINN + c) * COUTT + o]);
    }

    // kernel point owned by this lane (stage-1 B-frag col = low).
    // low==15 is the pad: sentinel far away -> w = max(1-sqrt(big),0) = 0.
    float px = 1e4f, py = 1e4f, pz = 1e4f;
    if (low < KNUM) { px = kpts[low * 3 + 0]; py = kpts[low * 3 + 1]; pz = kpts[low * 3 + 2]; }

    __syncthreads();

    for (int b = blockIdx.x; b < nBatch; b += gridDim.x) {
        // ================= stage 1: 4 points per wave =================
        for (int j = 0; j < 4; ++j) {
            const int p = wave * 4 + j;
            int n = b * 16 + p;
            if (n >= nPts) n = nPts - 1;   // tail clamp (loads only)

            // phase A: lanes 0..31 compute neighbor xyz (+ gather index in .w)
            if (lane < HH) {
                int e = edge[n * HH + lane];
                float sx = support[e * 3 + 0], sy = support[e * 3 + 1], sz = support[e * 3 + 2];
                float qx = query[n * 3 + 0],  qy = query[n * 3 + 1],  qz = query[n * 3 + 2];
                f32x4 v = { sx - qx, sy - qy, sz - qz, __int_as_float(e) };
                int slot = (lane & 24) | ((lane ^ (lane >> 3)) & 7);   // bank-spread swizzle
                xyz[wave][j & 1][slot] = v;
            }
            __syncthreads();

            // phase B: weights w[kk=low][h=g*8+i] -> stage-1 B-frag (w^T)
            short8 wf;
            int eidx[8];
            #pragma unroll
            for (int i = 0; i < 8; ++i) {
                int slot = (g << 3) | (i ^ g);
                f32x4 v = xyz[wave][j & 1][slot];
                eidx[i] = __float_as_int(v.w);
                float dx = v.x - px, dy = v.y - py, dz = v.z - pz;
                float d2 = dx * dx + dy * dy + dz * dz;
                float w  = fmaxf(1.f - sqrtf(d2), 0.f);
                wf[i] = (short)f2bf(w);
            }

            // phase C: feature A-frags (f^T): row c = low (+16), k-elem h = g*8+i
            short8 a0, a1;
            #pragma unroll
            for (int i = 0; i < 8; ++i) {
                const float* fr = feats + (long)eidx[i] * CINN + low;
                a0[i] = (short)f2bf(fr[0]);
                a1[i] = (short)f2bf(fr[16]);
            }

            // weighted^T[c][kk] = sum_h f[h][c] * w[kk][h]
            f32x4 c0 = {0.f, 0.f, 0.f, 0.f}, c1 = {0.f, 0.f, 0.f, 0.f};
            c0 = __builtin_amdgcn_mfma_f32_16x16x32_bf16(a0, wf, c0, 0, 0, 0);
            c1 = __builtin_amdgcn_mfma_f32_16x16x32_bf16(a1, wf, c1, 0, 0, 0);

            // phase D: pack bf16 + scatter into stage-2 A-frag LDS
            // C layout: col kk = low, row c_local = g*4 + r (tile0), +16 (tile1)
            int s = low;
            if (s < KNUM) {
                unsigned lo0 = (unsigned)f2bf(c0.x) | ((unsigned)f2bf(c0.y) << 16);
                unsigned hi0 = (unsigned)f2bf(c0.z) | ((unsigned)f2bf(c0.w) << 16);
                unsigned lo1 = (unsigned)f2bf(c1.x) | ((unsigned)f2bf(c1.y) << 16);
                unsigned hi1 = (unsigned)f2bf(c1.z) | ((unsigned)f2bf(c1.w) << 16);
                int ld0  = p + ((g >> 1) << 4);       // dest lane for tile0 (c>>3 = g>>1)
                int ld1  = ld0 + 32;                  // tile1: c += 16 -> +32 lanes
                int half = (g & 1) << 3;              // byte offset: i = (g&1)*4 + r
                int b0 = ((s * 64 + ld0) * 16 + half) ^ ((s & 7) << 4);
                int b1 = ((s * 64 + ld1) * 16 + half) ^ ((s & 7) << 4);
                *(u32x2*)((char*)af_lds + b0) = (u32x2){lo0, hi0};
                *(u32x2*)((char*)af_lds + b1) = (u32x2){lo1, hi1};
            }
        }
        __syncthreads();

        // ================= stage 2: out[p][o] = sum_s,c weighted * Kv =================
        f32x4 acc = {0.f, 0.f, 0.f, 0.f};
        const int tile = wave;
        #pragma unroll
        for (int s = 0; s < KNUM; ++s) {
            short8 av = *(const short8*)((const char*)af_lds +
                         (((s * 64 + lane) * 16) ^ ((s & 7) << 4)));
            short8 bv = *(const short8*)((const char*)kv_lds +
                         ((s * 4 + tile) * 64 + lane) * 16);
            acc = __builtin_amdgcn_mfma_f32_16x16x32_bf16(av, bv, acc, 0, 0, 0);
        }

        #pragma unroll
        for (int r = 0; r < 4; ++r) {
            int pp = g * 4 + r;              // C row = point
            int n  = b * 16 + pp;
            if (n < nPts) out[n * COUTT + tile * 16 + low] = acc[r];
        }
        __syncthreads();   // protect af_lds before next batch's stage-1
    }
}

extern "C" void kernel_launch(void* const* d_in, const int* in_sizes, int n_in,
                              void* d_out, int out_size, void* d_ws, size_t ws_size,
                              hipStream_t stream) {
    const float* query   = (const float*)d_in[0];
    const float* support = (const float*)d_in[1];
    const int*   edge    = (const int*)d_in[2];
    const float* feats   = (const float*)d_in[3];
    const float* kpts    = (const float*)d_in[4];
    const float* kvals   = (const float*)d_in[5];
    float* out = (float*)d_out;

    int nPts   = in_sizes[0] / 3;
    int nBatch = (nPts + 15) / 16;
    int grid   = 512;                 // persistent: 2 blocks/CU x 256 CU
    if (grid > nBatch) grid = nBatch;

    hipLaunchKernelGGL(kpconv_kernel, dim3(grid), dim3(256), 0, stream,
                       query, support, edge, feats, kpts, kvals, out, nPts, nBatch);
}

// Round 2
// 160.585 us; speedup vs baseline: 1.2479x; 1.2479x over previous
//
#include <hip/hip_runtime.h>
#include <hip/hip_bf16.h>

typedef __attribute__((ext_vector_type(8))) short short8;
typedef __attribute__((ext_vector_type(4))) short short4v;
typedef __attribute__((ext_vector_type(4))) float f32x4;
typedef __attribute__((ext_vector_type(2))) unsigned int u32x2;

#define HH   32
#define CINN 32
#define COUTT 64
#define KNUM 15

__device__ __forceinline__ unsigned short f2bf(float f) {
    unsigned u = __float_as_uint(f);
    u += 0x7fffu + ((u >> 16) & 1u);      // round-to-nearest-even
    return (unsigned short)(u >> 16);
}

// ---- pre-pass: feats f32 -> bf16 rows (one 64B cache line per row) ----
__global__ void cvt_feats_kernel(const float* __restrict__ f,
                                 unsigned short* __restrict__ o, int n4) {
    int i = blockIdx.x * blockDim.x + threadIdx.x;
    if (i < n4) {
        f32x4 v = *(const f32x4*)(f + i * 4);
        short4v s = { (short)f2bf(v.x), (short)f2bf(v.y),
                      (short)f2bf(v.z), (short)f2bf(v.w) };
        *(short4v*)(o + i * 4) = s;
    }
}

__launch_bounds__(256, 3)
__global__ void kpconv_kernel(const float* __restrict__ query,
                              const float* __restrict__ support,
                              const int*   __restrict__ edge,
                              const float* __restrict__ feats,
                              const unsigned short* __restrict__ featsbf,
                              const float* __restrict__ kpts,
                              const float* __restrict__ kvals,
                              float* __restrict__ out,
                              int nPts, int nBatch) {
    // LDS: stage-2 A-frags 15360B + xyz 4096B = 19456B
    __shared__ unsigned short af_lds[KNUM * 64 * 8];
    __shared__ f32x4 xyz[4][2][32];

    const int tid  = threadIdx.x;
    const int wave = tid >> 6;
    const int lane = tid & 63;
    const int g    = lane >> 4;
    const int low  = lane & 15;

    // ---- Kv -> registers, stage-2 B-frag order for this wave's o-tile ----
    // kvreg[s][i] = Kv[s][c=(lane>>4)*8+i][o=wave*16+(lane&15)]
    short8 kvreg[KNUM];
    #pragma unroll
    for (int s = 0; s < KNUM; ++s) {
        #pragma unroll
        for (int i = 0; i < 8; ++i) {
            int c = (g << 3) + i;
            int o = (wave << 4) + low;
            kvreg[s][i] = (short)f2bf(kvals[(s * CINN + c) * COUTT + o]);
        }
    }

    // kernel point owned by this lane (stage-1 B-frag col = low).
    // low==15 is the pad: sentinel far away -> w = 0.
    float px = 1e4f, py = 1e4f, pz = 1e4f;
    if (low < KNUM) { px = kpts[low * 3 + 0]; py = kpts[low * 3 + 1]; pz = kpts[low * 3 + 2]; }

    __syncthreads();

    for (int b = blockIdx.x; b < nBatch; b += gridDim.x) {
        // ================= stage 1: 4 points per wave (2 per half-wave load) ======
        for (int jj = 0; jj < 4; jj += 2) {
            // phase A: full wave gathers neighbors of points jj (lanes<32) and jj+1
            {
                int jpar = lane >> 5;
                int l32  = lane & 31;
                int n = b * 16 + wave * 4 + jj + jpar;
                if (n >= nPts) n = nPts - 1;
                int e = edge[n * HH + l32];
                float qx = query[n * 3 + 0], qy = query[n * 3 + 1], qz = query[n * 3 + 2];
                f32x4 v = { support[e * 3 + 0] - qx, support[e * 3 + 1] - qy,
                            support[e * 3 + 2] - qz, __int_as_float(e) };
                int slot = (l32 & 24) | ((l32 ^ (l32 >> 3)) & 7);   // bank-spread swizzle
                xyz[wave][jpar][slot] = v;
                // wave-private buffer: no barrier needed, compiler orders LDS ops
            }

            #pragma unroll
            for (int jp = 0; jp < 2; ++jp) {
                const int p = wave * 4 + jj + jp;

                // phase B: weights w[kk=low][h=g*8+i] -> stage-1 B-frag (w^T)
                short8 wf;
                int eidx[8];
                #pragma unroll
                for (int i = 0; i < 8; ++i) {
                    int slot = (g << 3) | (i ^ g);
                    f32x4 v = xyz[wave][jp][slot];
                    eidx[i] = __float_as_int(v.w);
                    float dx = v.x - px, dy = v.y - py, dz = v.z - pz;
                    float d2 = dx * dx + dy * dy + dz * dz;
                    float w  = fmaxf(1.f - sqrtf(d2), 0.f);
                    wf[i] = (short)f2bf(w);
                }

                // phase C: feature A-frags (f^T): row c = low (+16), k-elem h = g*8+i
                short8 a0, a1;
                if (featsbf) {
                    #pragma unroll
                    for (int i = 0; i < 8; ++i) {
                        const unsigned short* fr = featsbf + (long)eidx[i] * CINN;
                        a0[i] = (short)fr[low];
                        a1[i] = (short)fr[low + 16];
                    }
                } else {
                    #pragma unroll
                    for (int i = 0; i < 8; ++i) {
                        const float* fr = feats + (long)eidx[i] * CINN + low;
                        a0[i] = (short)f2bf(fr[0]);
                        a1[i] = (short)f2bf(fr[16]);
                    }
                }

                // weighted^T[c][kk] = sum_h f[h][c] * w[kk][h]
                f32x4 c0 = {0.f, 0.f, 0.f, 0.f}, c1 = {0.f, 0.f, 0.f, 0.f};
                c0 = __builtin_amdgcn_mfma_f32_16x16x32_bf16(a0, wf, c0, 0, 0, 0);
                c1 = __builtin_amdgcn_mfma_f32_16x16x32_bf16(a1, wf, c1, 0, 0, 0);

                // phase D: pack bf16 + scatter into stage-2 A-frag LDS
                // C layout: col kk = low, row c_local = g*4 + r (tile0), +16 (tile1)
                int s = low;
                if (s < KNUM) {
                    unsigned lo0 = (unsigned)f2bf(c0.x) | ((unsigned)f2bf(c0.y) << 16);
                    unsigned hi0 = (unsigned)f2bf(c0.z) | ((unsigned)f2bf(c0.w) << 16);
                    unsigned lo1 = (unsigned)f2bf(c1.x) | ((unsigned)f2bf(c1.y) << 16);
                    unsigned hi1 = (unsigned)f2bf(c1.z) | ((unsigned)f2bf(c1.w) << 16);
                    int ld0  = p + ((g >> 1) << 4);       // dest lane for tile0
                    int ld1  = ld0 + 32;                  // tile1: c += 16 -> +32 lanes
                    int half = (g & 1) << 3;              // byte offset: i = (g&1)*4 + r
                    int b0 = ((s * 64 + ld0) * 16 + half) ^ ((s & 7) << 4);
                    int b1 = ((s * 64 + ld1) * 16 + half) ^ ((s & 7) << 4);
                    *(u32x2*)((char*)af_lds + b0) = (u32x2){lo0, hi0};
                    *(u32x2*)((char*)af_lds + b1) = (u32x2){lo1, hi1};
                }
            }
        }
        __syncthreads();

        // ================= stage 2: out[p][o] = sum_s,c weighted * Kv =================
        f32x4 acc = {0.f, 0.f, 0.f, 0.f};
        #pragma unroll
        for (int s = 0; s < KNUM; ++s) {
            short8 av = *(const short8*)((const char*)af_lds +
                         (((s * 64 + lane) * 16) ^ ((s & 7) << 4)));
            acc = __builtin_amdgcn_mfma_f32_16x16x32_bf16(av, kvreg[s], acc, 0, 0, 0);
        }

        #pragma unroll
        for (int r = 0; r < 4; ++r) {
            int pp = g * 4 + r;              // C row = point
            int n  = b * 16 + pp;
            if (n < nPts) out[n * COUTT + (wave << 4) + low] = acc[r];
        }
        __syncthreads();   // protect af_lds before next batch's stage-1
    }
}

extern "C" void kernel_launch(void* const* d_in, const int* in_sizes, int n_in,
                              void* d_out, int out_size, void* d_ws, size_t ws_size,
                              hipStream_t stream) {
    const float* query   = (const float*)d_in[0];
    const float* support = (const float*)d_in[1];
    const int*   edge    = (const int*)d_in[2];
    const float* feats   = (const float*)d_in[3];
    const float* kpts    = (const float*)d_in[4];
    const float* kvals   = (const float*)d_in[5];
    float* out = (float*)d_out;

    int nPts   = in_sizes[0] / 3;
    int nBatch = (nPts + 15) / 16;

    // pre-pass: bf16 feature rows in workspace (one 64B line per row)
    size_t need = (size_t)nPts * CINN * sizeof(unsigned short);
    unsigned short* featsbf = nullptr;
    if (ws_size >= need) {
        featsbf = (unsigned short*)d_ws;
        int n4 = nPts * CINN / 4;
        hipLaunchKernelGGL(cvt_feats_kernel, dim3((n4 + 255) / 256), dim3(256), 0, stream,
                           feats, featsbf, n4);
    }

    int grid = 768;                 // persistent: 3 blocks/CU x 256 CU
    if (grid > nBatch) grid = nBatch;

    hipLaunchKernelGGL(kpconv_kernel, dim3(grid), dim3(256), 0, stream,
                       query, support, edge, feats, featsbf, kpts, kvals, out, nPts, nBatch);
}

// Round 3
// 158.353 us; speedup vs baseline: 1.2655x; 1.0141x over previous
//
#include <hip/hip_runtime.h>
#include <hip/hip_bf16.h>

typedef __attribute__((ext_vector_type(8))) short short8;
typedef __attribute__((ext_vector_type(4))) short short4v;
typedef __attribute__((ext_vector_type(4))) float f32x4;
typedef __attribute__((ext_vector_type(4))) int   i32x4;
typedef __attribute__((ext_vector_type(2))) unsigned int u32x2;

#define HH    32
#define CINN  32
#define COUTT 64
#define KNUM  15

__device__ __forceinline__ short bfbits(float f) {
    __hip_bfloat16 h = __float2bfloat16(f);   // RNE, hw cvt
    short s; __builtin_memcpy(&s, &h, 2); return s;
}

// ---- pre-pass: feats f32 -> bf16 rows (one 64B cache line per row) ----
__global__ void cvt_feats_kernel(const float* __restrict__ f,
                                 unsigned short* __restrict__ o, int n4) {
    int i = blockIdx.x * blockDim.x + threadIdx.x;
    if (i < n4) {
        f32x4 v = *(const f32x4*)(f + i * 4);
        short4v s = { bfbits(v.x), bfbits(v.y), bfbits(v.z), bfbits(v.w) };
        *(short4v*)(o + i * 4) = s;
    }
}

__launch_bounds__(256, 4)
__global__ void kpconv_kernel(const float* __restrict__ query,
                              const float* __restrict__ support,
                              const int*   __restrict__ edge,
                              const unsigned short* __restrict__ featsbf,
                              const float* __restrict__ kpts,
                              const float* __restrict__ kvals,
                              float* __restrict__ out,
                              int nPts, int nBatch) {
    // LDS: af 15360 + xyz 8192 = 23552 B -> 4 blocks/CU fine
    __shared__ unsigned short af_lds[KNUM * 64 * 8];
    __shared__ f32x4 xyz[4][4][32];     // [wave][point][h-slot], XOR-swizzled bytes

    const int tid  = threadIdx.x;
    const int wave = tid >> 6;
    const int lane = tid & 63;
    const int g    = lane >> 4;
    const int low  = lane & 15;

    // ---- Kv -> registers, stage-2 B-frag order, even/odd channel permutation ----
    // k-index c' = g*8+i  ->  channel = 2*(c'&15) + (c'>>4)
    short8 kvreg[KNUM];
    #pragma unroll
    for (int s = 0; s < KNUM; ++s) {
        #pragma unroll
        for (int i = 0; i < 8; ++i) {
            int cp   = (g << 3) + i;
            int chan = (((cp & 15) << 1) | (cp >> 4));
            int o    = (wave << 4) + low;
            kvreg[s][i] = bfbits(kvals[(s * CINN + chan) * COUTT + o]);
        }
    }

    // lane's kernel point (stage-1 B-frag col = low); low==15 pad -> w=0 sentinel
    float px = 1e4f, py = 1e4f, pz = 1e4f;
    if (low < KNUM) { px = kpts[low * 3 + 0]; py = kpts[low * 3 + 1]; pz = kpts[low * 3 + 2]; }
    const float m2px = -2.f * px, m2py = -2.f * py, m2pz = -2.f * pz;
    const float pp2  = px * px + py * py + pz * pz;

    __syncthreads();

    for (int b = blockIdx.x; b < nBatch; b += gridDim.x) {
        const int nbase = b * 16 + wave * 4;

        // ===== phase A: gather neighbor offsets for all 4 points (2 per pass) =====
        #pragma unroll
        for (int jj = 0; jj < 4; jj += 2) {
            int jpar = lane >> 5;
            int l32  = lane & 31;
            int n = nbase + jj + jpar;
            int e = edge[n * HH + l32];
            float qx = query[n * 3 + 0], qy = query[n * 3 + 1], qz = query[n * 3 + 2];
            float dx = support[e * 3 + 0] - qx;
            float dy = support[e * 3 + 1] - qy;
            float dz = support[e * 3 + 2] - qz;
            float nn = dx * dx + dy * dy + dz * dz;
            f32x4 v = { dx, dy, dz, nn };
            int sw = (l32 << 4) ^ ((l32 >> 3) << 4);          // bank-spread, 16B-aligned
            *(f32x4*)((char*)&xyz[wave][jj + jpar][0] + sw) = v;
        }

        // ===== stage 1: 4 points per wave =====
        #pragma unroll
        for (int p = 0; p < 4; ++p) {
            const int n = nbase + p;

            // edge indices for this lane's quarter: h = g*8 .. g*8+7 (broadcast loads)
            const int* erow = edge + n * HH + (g << 3);
            i32x4 e0 = *(const i32x4*)erow;
            i32x4 e1 = *(const i32x4*)(erow + 4);

            // feature gathers: one dword = channels {2*low, 2*low+1} of row e
            unsigned fd[8];
            #pragma unroll
            for (int i = 0; i < 8; ++i) {
                int e = (i < 4) ? e0[i & 3] : e1[i & 3];
                fd[i] = *(const unsigned*)((const char*)featsbf + ((long)e << 6) + (low << 2));
            }

            // weights w[kk=low][h=g*8+i]  (stage-1 B-frag, w^T)
            short8 wf;
            const char* xb = (const char*)&xyz[wave][p][0];
            #pragma unroll
            for (int i = 0; i < 8; ++i) {
                int s = (g << 3) + i;
                f32x4 v = *(const f32x4*)(xb + ((s << 4) ^ (g << 4)));
                float d2 = fmaf(v.x, m2px, fmaf(v.y, m2py, fmaf(v.z, m2pz, v.w + pp2)));
                float w  = fmaxf(1.f - sqrtf(d2), 0.f);
                wf[i] = bfbits(w);
            }

            // A-frags: a0 row=low -> channel 2*low, a1 row=low -> channel 2*low+1
            short8 a0, a1;
            #pragma unroll
            for (int i = 0; i < 8; ++i) {
                a0[i] = (short)(fd[i] & 0xffffu);
                a1[i] = (short)(fd[i] >> 16);
            }

            f32x4 c0 = {0.f, 0.f, 0.f, 0.f}, c1 = {0.f, 0.f, 0.f, 0.f};
            c0 = __builtin_amdgcn_mfma_f32_16x16x32_bf16(a0, wf, c0, 0, 0, 0);
            c1 = __builtin_amdgcn_mfma_f32_16x16x32_bf16(a1, wf, c1, 0, 0, 0);

            // scatter weighted^T (permuted-channel rows) into stage-2 A-frag LDS
            int s = low;
            if (s < KNUM) {
                unsigned lo0 = (unsigned)(unsigned short)bfbits(c0.x) | ((unsigned)(unsigned short)bfbits(c0.y) << 16);
                unsigned hi0 = (unsigned)(unsigned short)bfbits(c0.z) | ((unsigned)(unsigned short)bfbits(c0.w) << 16);
                unsigned lo1 = (unsigned)(unsigned short)bfbits(c1.x) | ((unsigned)(unsigned short)bfbits(c1.y) << 16);
                unsigned hi1 = (unsigned)(unsigned short)bfbits(c1.z) | ((unsigned)(unsigned short)bfbits(c1.w) << 16);
                int ld0  = (wave << 2) + p + ((g >> 1) << 4);   // dest lane, tile0
                int ld1  = ld0 + 32;                             // tile1 (+16 rows)
                int half = (g & 1) << 3;
                int b0 = ((s * 64 + ld0) * 16 + half) ^ ((s & 7) << 4);
                int b1 = ((s * 64 + ld1) * 16 + half) ^ ((s & 7) << 4);
                *(u32x2*)((char*)af_lds + b0) = (u32x2){lo0, hi0};
                *(u32x2*)((char*)af_lds + b1) = (u32x2){lo1, hi1};
            }
        }
        __syncthreads();

        // ===== stage 2: out[p][o] = sum_s,c' weighted[p][c'] * Kv[s][pi(c')][o] =====
        f32x4 acc = {0.f, 0.f, 0.f, 0.f};
        #pragma unroll
        for (int s = 0; s < KNUM; ++s) {
            short8 av = *(const short8*)((const char*)af_lds +
                         (((s * 64 + lane) * 16) ^ ((s & 7) << 4)));
            acc = __builtin_amdgcn_mfma_f32_16x16x32_bf16(av, kvreg[s], acc, 0, 0, 0);
        }

        #pragma unroll
        for (int r = 0; r < 4; ++r) {
            int pp = (g << 2) + r;           // C row = point
            int n  = b * 16 + pp;
            if (n < nPts) out[n * COUTT + (wave << 4) + low] = acc[r];
        }
        __syncthreads();   // protect af_lds before next batch's stage-1
    }
}

extern "C" void kernel_launch(void* const* d_in, const int* in_sizes, int n_in,
                              void* d_out, int out_size, void* d_ws, size_t ws_size,
                              hipStream_t stream) {
    const float* query   = (const float*)d_in[0];
    const float* support = (const float*)d_in[1];
    const int*   edge    = (const int*)d_in[2];
    const float* feats   = (const float*)d_in[3];
    const float* kpts    = (const float*)d_in[4];
    const float* kvals   = (const float*)d_in[5];
    float* out = (float*)d_out;

    int nPts   = in_sizes[0] / 3;
    int nBatch = (nPts + 15) / 16;

    // pre-pass: bf16 feature rows (64B per row)
    unsigned short* featsbf = (unsigned short*)d_ws;
    int n4 = nPts * CINN / 4;
    hipLaunchKernelGGL(cvt_feats_kernel, dim3((n4 + 255) / 256), dim3(256), 0, stream,
                       feats, featsbf, n4);

    int grid = 1024;                 // persistent: 4 blocks/CU x 256 CU
    if (grid > nBatch) grid = nBatch;

    hipLaunchKernelGGL(kpconv_kernel, dim3(grid), dim3(256), 0, stream,
                       query, support, edge, featsbf, kpts, kvals, out, nPts, nBatch);
}